// Round 7
// baseline (227.577 us; speedup 1.0000x reference)
//
#include <hip/hip_runtime.h>
#include <stdint.h>

// DfOp v7: v6 block-role split, but the passthrough role streams its reads
// through the LDS-DMA path (global_load_lds dwordx4) instead of demand
// loads. Six rounds of nulls (87-95 us for every schedule, 198-350 MB) and
// Little's law (~5 KB read data in flight per CU at ~1100 cy latency) point
// at a per-CU outstanding-miss cap on the demand-load return path. The DMA
// path is the one read mechanism not yet tried; it is the deep-queue
// staging path used by every fast gfx950 GEMM. Filt role + f2 tails are
// byte-identical to v6 => clean A/B isolating the read mechanism.
// Pass role: per block 8 rows, per row 192 aligned float4 (start 192 or 194
// by row parity) + 1 leftover float2. 4 waves x 6 DMA x 1 KB = 24576 B LDS,
// wave-private chunks (no barrier; vmcnt(0) + ds_read_b128 + store).

#define BN    8
#define TN    3000
#define FN    481
#define NDF   96
#define NORD  5
#define ROWF  (FN * 2)        // 962 floats per (b,t) row
#define THALF (TN / 2)        // 1500 t-pairs
#define NROWS (BN * TN)       // 24000 rows
#define RPB   8               // rows per passthrough block
#define NPB   (NROWS / RPB)   // 3000 passthrough blocks
#define NFB   ((BN * THALF * NDF) / 256)  // 4500 filt blocks (exact)

typedef float f2 __attribute__((ext_vector_type(2)));
typedef const void __attribute__((address_space(1)))* gas_t;
typedef void __attribute__((address_space(3)))* las_t;

__global__ __launch_bounds__(256) void df_kernel(const float* __restrict__ spec,
                                                 const float* __restrict__ coef,
                                                 float* __restrict__ out) {
    __shared__ float lds[6144];          // 24576 B = 4 waves x 6 chunks x 1024 B
    const int tid = threadIdx.x;
    const int m   = blockIdx.x % 5;

    if (m < 2) {
        // ---- passthrough role: copy bins [96,481) of 8 rows via LDS-DMA ----
        const int p  = (blockIdx.x / 5) * 2 + m;   // [0, 3000)
        const int r0 = p * RPB;
        const int w  = tid >> 6;                   // wave id 0..3
        const int l  = tid & 63;                   // lane

        // stage: 6 wave-level DMAs, 1 KB each (lane l -> ldsbase + l*16)
        #pragma unroll
        for (int j = 0; j < 6; ++j) {
            const int g  = (w * 6 + j) * 64 + l;   // f4 unit 0..1535
            const int rl = g / 192;                // row within block
            const int k  = g - rl * 192;           // f4 within row
            const int r  = r0 + rl;
            // aligned f4 region starts at float 192 (even r) / 194 (odd r)
            const int fidx = ROWF * r + 192 + ((r & 1) << 1) + (k << 2);
            __builtin_amdgcn_global_load_lds((gas_t)(spec + fidx),
                                             (las_t)(&lds[(w * 6 + j) * 256]),
                                             16, 0, 0);
        }

        // leftover f2 per row (demand load; 8 lanes only)
        f2 e; int eidx = 0;
        if (tid < RPB) {
            const int r = r0 + tid;
            eidx = ROWF * r + ((r & 1) ? 192 : 960);
            e = *(const f2*)(spec + eidx);
        }

        // wave-private staging: no barrier needed, just drain the DMA queue
        asm volatile("s_waitcnt vmcnt(0)" ::: "memory");
        __builtin_amdgcn_sched_barrier(0);

        #pragma unroll
        for (int j = 0; j < 6; ++j) {
            const float4 x = *(const float4*)&lds[(w * 6 + j) * 256 + l * 4];
            const int g  = (w * 6 + j) * 64 + l;
            const int rl = g / 192;
            const int k  = g - rl * 192;
            const int r  = r0 + rl;
            const int fidx = ROWF * r + 192 + ((r & 1) << 1) + (k << 2);
            *(float4*)(out + fidx) = x;
        }
        if (tid < RPB) *(f2*)(out + eidx) = e;
    } else {
        // ---- filt role: bins [0,96), pair of consecutive t per thread ----
        // (byte-identical to v6)
        const int q = (blockIdx.x / 5) * 3 + (m - 2);  // [0, 4500)
        const int i = q * 256 + tid;                   // < 1,152,000 exactly

        const int f   = i % NDF;
        const int bth = i / NDF;
        const int th  = bth % THALF;
        const int b   = bth / THALF;
        const int t0  = th * 2;
        const int bt0   = b * TN + t0;
        const int base0 = bt0 * ROWF + f * 2;          // (b,t0,f,0)

        const f2* cp = (const f2*)(coef + (bt0 * NDF + f) * (2 * NORD));
        const f2* cq = cp + NDF * NORD;                // next t row's coef
        const f2 c0a = cp[0], c0b = cp[1], c0c = cp[2], c0d = cp[3], c0e = cp[4];
        const f2 c1a = cq[0], c1b = cq[1], c1c = cq[2], c1d = cq[3], c1e = cq[4];

        const float* sp = spec + base0;
        f2 x0, x1, x2, x3, x4, x5;                     // rows t0-4 .. t0+1
        if (t0 >= NORD - 1) {                          // fast path
            x0 = *(const f2*)(sp - 4 * ROWF);
            x1 = *(const f2*)(sp - 3 * ROWF);
            x2 = *(const f2*)(sp - 2 * ROWF);
            x3 = *(const f2*)(sp - 1 * ROWF);
            x4 = *(const f2*)(sp);
            x5 = *(const f2*)(sp + 1 * ROWF);
        } else {                                       // t0 in {0,2}
            const f2 z = {0.f, 0.f};
            x0 = (t0 >= 4) ? *(const f2*)(sp - 4 * ROWF) : z;
            x1 = (t0 >= 3) ? *(const f2*)(sp - 3 * ROWF) : z;
            x2 = (t0 >= 2) ? *(const f2*)(sp - 2 * ROWF) : z;
            x3 = (t0 >= 1) ? *(const f2*)(sp - 1 * ROWF) : z;
            x4 = *(const f2*)(sp);
            x5 = *(const f2*)(sp + 1 * ROWF);
        }

        float fr0, fi0, fr1, fi1;
        {   // t0: taps x0..x4, coef c0 (cr[k]=coef[k], ci[k]=coef[5+k])
            const float cr0 = c0a.x, cr1 = c0a.y, cr2 = c0b.x, cr3 = c0b.y, cr4 = c0c.x;
            const float ci0 = c0c.y, ci1 = c0d.x, ci2 = c0d.y, ci3 = c0e.x, ci4 = c0e.y;
            fr0 = x0.x*cr0 - x0.y*ci0; fi0 = x0.x*ci0 + x0.y*cr0;
            fr0 += x1.x*cr1 - x1.y*ci1; fi0 += x1.x*ci1 + x1.y*cr1;
            fr0 += x2.x*cr2 - x2.y*ci2; fi0 += x2.x*ci2 + x2.y*cr2;
            fr0 += x3.x*cr3 - x3.y*ci3; fi0 += x3.x*ci3 + x3.y*cr3;
            fr0 += x4.x*cr4 - x4.y*ci4; fi0 += x4.x*ci4 + x4.y*cr4;
        }
        {   // t0+1: taps x1..x5, coef c1
            const float cr0 = c1a.x, cr1 = c1a.y, cr2 = c1b.x, cr3 = c1b.y, cr4 = c1c.x;
            const float ci0 = c1c.y, ci1 = c1d.x, ci2 = c1d.y, ci3 = c1e.x, ci4 = c1e.y;
            fr1 = x1.x*cr0 - x1.y*ci0; fi1 = x1.x*ci0 + x1.y*cr0;
            fr1 += x2.x*cr1 - x2.y*ci1; fi1 += x2.x*ci1 + x2.y*cr1;
            fr1 += x3.x*cr2 - x3.y*ci2; fi1 += x3.x*ci2 + x3.y*cr2;
            fr1 += x4.x*cr3 - x4.y*ci3; fi1 += x4.x*ci3 + x4.y*cr3;
            fr1 += x5.x*cr4 - x5.y*ci4; fi1 += x5.x*ci4 + x5.y*cr4;
        }

        *(f2*)(out + base0)        = (f2){fr0, fi0};
        *(f2*)(out + base0 + ROWF) = (f2){fr1, fi1};
    }
}

extern "C" void kernel_launch(void* const* d_in, const int* in_sizes, int n_in,
                              void* d_out, int out_size, void* d_ws, size_t ws_size,
                              hipStream_t stream) {
    const float* spec = (const float*)d_in[0];
    const float* coef = (const float*)d_in[1];
    float* out = (float*)d_out;

    const int grid = NPB + NFB;        // 3000 + 4500 = 7500 (%5 == 0)
    df_kernel<<<grid, 256, 0, stream>>>(spec, coef, out);
}